// Round 4
// baseline (290.288 us; speedup 1.0000x reference)
//
#include <hip/hip_runtime.h>
#include <cstdint>
#include <cstddef>

#define RADIX 258
#define EMPTY_ENTRY 0xFFFFFFFFFFFFFFFFULL
#define MAP_DIM 128                 // down coords are even, 0..254 -> /2 in 0..127
#define MAP_SLOTS (2 * MAP_DIM * MAP_DIM * MAP_DIM)   // 4.19M slots = 16 MiB
#define NB_STRIDE 32                // u32 words per out row: [cnt, idx0..26, pad] = 128 B

typedef float f32x4 __attribute__((ext_vector_type(4)));

// ---------------------------------------------------------------------------
// FAST PATH: dense parent map + one-cache-line neighbor lists + gather
// ---------------------------------------------------------------------------

// One kernel clears both: map -> 0xFF (uint4 stores), nbmap word0 (cnt) -> 0.
__global__ __launch_bounds__(256) void clear_kernel(
    unsigned* __restrict__ map, unsigned* __restrict__ nbmap, int M)
{
    int t = blockIdx.x * blockDim.x + threadIdx.x;
    const int mapVec = MAP_SLOTS / 4;
    if (t < mapVec) {
        ((uint4*)map)[t] = make_uint4(0xFFFFFFFFu, 0xFFFFFFFFu, 0xFFFFFFFFu, 0xFFFFFFFFu);
    }
    int u = t - mapVec;
    if (u >= 0 && u < M) nbmap[(size_t)u * NB_STRIDE] = 0u;
}

__global__ __launch_bounds__(256) void build_map_kernel(
    const int* __restrict__ down, int M, unsigned* __restrict__ map)
{
    int j = blockIdx.x * blockDim.x + threadIdx.x;
    if (j >= M) return;
    const int4 c = ((const int4*)down)[j];
    unsigned idx = (((unsigned)(c.w * MAP_DIM + (c.x >> 1)) * MAP_DIM)
                    + (unsigned)(c.y >> 1)) * MAP_DIM + (unsigned)(c.z >> 1);
    map[idx] = (unsigned)j;
}

// Each input voxel appends its row index into the single-line list of every
// existing candidate parent (even axis -> 1 candidate, odd axis -> 2).
// cnt lives in word 0 of the same 128-B line as the indices.
__global__ __launch_bounds__(256) void scatter_kernel(
    const int* __restrict__ coords, int N,
    const unsigned* __restrict__ map,
    unsigned* __restrict__ nbmap)
{
    int i = blockIdx.x * blockDim.x + threadIdx.x;
    if (i >= N) return;
    const int4 c = ((const int4*)coords)[i];
    int qx[2], qy[2], qz[2];
    int nx = 1, ny = 1, nz = 1;
    if (c.x & 1) { qx[0] = (c.x - 1) >> 1; if (c.x + 1 <= 254) qx[nx++] = (c.x + 1) >> 1; }
    else         { qx[0] = c.x >> 1; }
    if (c.y & 1) { qy[0] = (c.y - 1) >> 1; if (c.y + 1 <= 254) qy[ny++] = (c.y + 1) >> 1; }
    else         { qy[0] = c.y >> 1; }
    if (c.z & 1) { qz[0] = (c.z - 1) >> 1; if (c.z + 1 <= 254) qz[nz++] = (c.z + 1) >> 1; }
    else         { qz[0] = c.z >> 1; }
    unsigned bbase = (unsigned)(c.w * MAP_DIM);
    for (int ix = 0; ix < nx; ++ix) {
        unsigned xb = (bbase + (unsigned)qx[ix]) * MAP_DIM;
        for (int iy = 0; iy < ny; ++iy) {
            unsigned yb = (xb + (unsigned)qy[iy]) * MAP_DIM;
            for (int iz = 0; iz < nz; ++iz) {
                unsigned qi = map[yb + (unsigned)qz[iz]];
                if (qi != 0xFFFFFFFFu) {
                    unsigned pos = atomicAdd(&nbmap[(size_t)qi * NB_STRIDE], 1u);
                    nbmap[(size_t)qi * NB_STRIDE + 1 + pos] = (unsigned)i;
                }
            }
        }
    }
}

// One wave = 4 output rows (16-lane groups; lane j = channel quad j).
// Per row: ONE nontemporal 64-B line load gives cnt (word 0, via shfl) and
// indices 0..14 (words 1..15). Feats loads are exec-predicated on h<c
// (no duplicate gathers); indices >=15 (P < 1e-9 at avg c=1.9) fall back to
// a direct line read.
__global__ __launch_bounds__(256) void gather_kernel(
    const float* __restrict__ feats,
    const unsigned* __restrict__ nbmap,
    float* __restrict__ out, int M, int nwg)
{
    // bijective XCD-chunked block swizzle (8 XCDs)
    int bid = blockIdx.x;
    int q = nwg >> 3, r = nwg & 7;
    int xcd = bid & 7, orig = bid >> 3;
    int swz = (xcd < r ? xcd * (q + 1) : r * (q + 1) + (xcd - r) * q) + orig;

    int lane = threadIdx.x & 63;
    int g    = lane >> 4;          // row within this wave's quad
    int j    = lane & 15;          // channel quad
    int wave = swz * 4 + (int)(threadIdx.x >> 6);
    int row  = wave * 4 + g;
    bool valid = row < M;

    unsigned w = 0;
    if (valid) w = __builtin_nontemporal_load(&nbmap[(size_t)row * NB_STRIDE + j]);
    int gb = g << 4;
    int c = __shfl((int)w, gb);    // word 0 = count (uniform within group)

    const f32x4* f4 = (const f32x4*)feats;
    f32x4 acc = {-INFINITY, -INFINITY, -INFINITY, -INFINITY};
    for (int r4 = 0; r4 < c; r4 += 4) {
#pragma unroll
        for (int k = 0; k < 4; ++k) {
            int h = r4 + k;
            if (h < c) {
                int s = (h < 15) ? __shfl((int)w, gb + 1 + h)
                                 : (int)nbmap[(size_t)row * NB_STRIDE + 1 + h];
                f32x4 v = f4[(size_t)s * 16 + j];
                acc.x = fmaxf(acc.x, v.x);
                acc.y = fmaxf(acc.y, v.y);
                acc.z = fmaxf(acc.z, v.z);
                acc.w = fmaxf(acc.w, v.w);
            }
        }
    }
    if (valid) {
        if (c == 0) acc = (f32x4){0.f, 0.f, 0.f, 0.f};   // defensive (cannot happen)
        __builtin_nontemporal_store(acc, (f32x4*)out + (size_t)row * 16 + j);
    }
}

// ---------------------------------------------------------------------------
// FALLBACK PATH (round-1 proven kernels) if ws is too small
// ---------------------------------------------------------------------------

__global__ __launch_bounds__(256) void build_hash_kernel(
    const int* __restrict__ coords, int N,
    unsigned long long* __restrict__ tab, unsigned tmask, int tshift)
{
    int i = blockIdx.x * blockDim.x + threadIdx.x;
    if (i >= N) return;
    int x = coords[i * 4 + 0];
    int y = coords[i * 4 + 1];
    int z = coords[i * 4 + 2];
    int b = coords[i * 4 + 3];
    unsigned key = ((unsigned)(b * RADIX + x + 1) * RADIX + (unsigned)(y + 1)) * RADIX
                   + (unsigned)(z + 1);
    unsigned long long entry = ((unsigned long long)key << 32) | (unsigned)i;
    unsigned slot = (key * 2654435761u) >> tshift;
    while (true) {
        unsigned long long prev = atomicCAS(&tab[slot], EMPTY_ENTRY, entry);
        if (prev == EMPTY_ENTRY) break;
        slot = (slot + 1) & tmask;
    }
}

__global__ __launch_bounds__(256) void pool_kernel(
    const float* __restrict__ feats,
    const int* __restrict__ down, int M,
    const unsigned long long* __restrict__ tab, unsigned tmask, int tshift,
    float* __restrict__ out)
{
    int wave = (int)((blockIdx.x * blockDim.x + threadIdx.x) >> 6);
    int lane = threadIdx.x & 63;
    if (wave >= M) return;

    const int* dc = down + (size_t)wave * 4;
    int dx = dc[0], dy = dc[1], dz = dc[2], db = dc[3];
    unsigned base = ((unsigned)(db * RADIX + dx + 1) * RADIX + (unsigned)(dy + 1)) * RADIX
                    + (unsigned)(dz + 1);

    int src = -1;
    if (lane < 27) {
        int ox = lane % 3 - 1;
        int oy = (lane / 3) % 3 - 1;
        int oz = lane / 9 - 1;
        int delta = ox * (RADIX * RADIX) + oy * RADIX + oz;
        unsigned key = (unsigned)((int)base + delta);
        unsigned slot = (key * 2654435761u) >> tshift;
        while (true) {
            unsigned long long e = tab[slot];
            if (e == EMPTY_ENTRY) break;
            if ((unsigned)(e >> 32) == key) { src = (int)(unsigned)e; break; }
            slot = (slot + 1) & tmask;
        }
    }
    unsigned long long mask = __ballot(src >= 0);
    float acc = -INFINITY;
    while (mask) {
        int bit = __ffsll(mask) - 1;
        int s = __shfl(src, bit);
        acc = fmaxf(acc, feats[(size_t)s * 64 + lane]);
        mask &= mask - 1;
    }
    out[(size_t)wave * 64 + lane] = isinf(acc) ? 0.0f : acc;
}

// ---------------------------------------------------------------------------

extern "C" void kernel_launch(void* const* d_in, const int* in_sizes, int n_in,
                              void* d_out, int out_size, void* d_ws, size_t ws_size,
                              hipStream_t stream)
{
    const float* feats  = (const float*)d_in[0];
    const int*   coords = (const int*)d_in[1];
    const int*   down   = (const int*)d_in[2];
    float*       out    = (float*)d_out;

    int N = in_sizes[1] / 4;
    int M = in_sizes[2] / 4;

    size_t map_bytes = (size_t)MAP_SLOTS * 4;                   // 16 MiB
    size_t nb_bytes  = (size_t)((M + 15) & ~15) * NB_STRIDE * 4; // 128 B per row
    size_t need = map_bytes + nb_bytes;                          // ~147 MB

    if (ws_size >= need) {
        unsigned* map   = (unsigned*)d_ws;
        unsigned* nbmap = (unsigned*)((char*)d_ws + map_bytes);

        int clearThreads = MAP_SLOTS / 4 + M;
        clear_kernel<<<(clearThreads + 255) / 256, 256, 0, stream>>>(map, nbmap, M);
        build_map_kernel<<<(M + 255) / 256, 256, 0, stream>>>(down, M, map);
        scatter_kernel<<<(N + 255) / 256, 256, 0, stream>>>(coords, N, map, nbmap);

        int nwg = (M + 15) / 16;                  // 16 rows per 256-thread block
        gather_kernel<<<nwg, 256, 0, stream>>>(feats, nbmap, out, M, nwg);
    } else {
        int logT = 22;
        while (logT > 19 && ((size_t)8u << logT) > ws_size) logT--;
        unsigned T = 1u << logT;
        unsigned tmask = T - 1u;
        int tshift = 32 - logT;
        unsigned long long* tab = (unsigned long long*)d_ws;
        hipMemsetAsync(tab, 0xFF, (size_t)T * 8, stream);
        build_hash_kernel<<<(N + 255) / 256, 256, 0, stream>>>(coords, N, tab, tmask, tshift);
        pool_kernel<<<(M * 64 + 255) / 256, 256, 0, stream>>>(
            feats, down, M, tab, tmask, tshift, out);
    }
}

// Round 5
// 223.412 us; speedup vs baseline: 1.2993x; 1.2993x over previous
//
#include <hip/hip_runtime.h>
#include <cstdint>
#include <cstddef>

#define RADIX 258
#define EMPTY_ENTRY 0xFFFFFFFFFFFFFFFFULL
#define MAP_DIM 128                 // down coords are even, 0..254 -> /2 in 0..127
#define MAP_SLOTS (2 * MAP_DIM * MAP_DIM * MAP_DIM)   // 4.19M slots = 16 MiB
#define NB_STRIDE 32                // u32 words per out row (128-B aligned line);
                                    // word 0 unused, indices at words 1..27

typedef float f32x4 __attribute__((ext_vector_type(4)));

// ---------------------------------------------------------------------------
// FAST PATH: dense parent map + compact cnt + line-aligned nbmap + pipelined gather
// ---------------------------------------------------------------------------

__global__ __launch_bounds__(256) void build_map_kernel(
    const int* __restrict__ down, int M, unsigned* __restrict__ map)
{
    int j = blockIdx.x * blockDim.x + threadIdx.x;
    if (j >= M) return;
    const int4 c = ((const int4*)down)[j];
    unsigned idx = (((unsigned)(c.w * MAP_DIM + (c.x >> 1)) * MAP_DIM)
                    + (unsigned)(c.y >> 1)) * MAP_DIM + (unsigned)(c.z >> 1);
    map[idx] = (unsigned)j;
}

// Each input voxel appends its row index to every existing candidate parent's
// list. cnt is a separate compact array (4.2 MB -> L2-resident atomics);
// indices land in the row's 128-B-aligned nbmap line at word 1+pos.
__global__ __launch_bounds__(256) void scatter_kernel(
    const int* __restrict__ coords, int N,
    const unsigned* __restrict__ map,
    unsigned* __restrict__ cnt, unsigned* __restrict__ nbmap)
{
    int i = blockIdx.x * blockDim.x + threadIdx.x;
    if (i >= N) return;
    const int4 c = ((const int4*)coords)[i];
    int qx[2], qy[2], qz[2];
    int nx = 1, ny = 1, nz = 1;
    if (c.x & 1) { qx[0] = (c.x - 1) >> 1; if (c.x + 1 <= 254) qx[nx++] = (c.x + 1) >> 1; }
    else         { qx[0] = c.x >> 1; }
    if (c.y & 1) { qy[0] = (c.y - 1) >> 1; if (c.y + 1 <= 254) qy[ny++] = (c.y + 1) >> 1; }
    else         { qy[0] = c.y >> 1; }
    if (c.z & 1) { qz[0] = (c.z - 1) >> 1; if (c.z + 1 <= 254) qz[nz++] = (c.z + 1) >> 1; }
    else         { qz[0] = c.z >> 1; }
    unsigned bbase = (unsigned)(c.w * MAP_DIM);
    for (int ix = 0; ix < nx; ++ix) {
        unsigned xb = (bbase + (unsigned)qx[ix]) * MAP_DIM;
        for (int iy = 0; iy < ny; ++iy) {
            unsigned yb = (xb + (unsigned)qy[iy]) * MAP_DIM;
            for (int iz = 0; iz < nz; ++iz) {
                unsigned qi = map[yb + (unsigned)qz[iz]];
                if (qi != 0xFFFFFFFFu) {
                    unsigned pos = atomicAdd(&cnt[qi], 1u);
                    nbmap[(size_t)qi * NB_STRIDE + 1 + pos] = (unsigned)i;
                }
            }
        }
    }
}

// Persistent grid-stride gather, 4 rows per wave-iteration (16-lane groups;
// lane j = channel quad j). Lane gb+0 loads cnt, lanes gb+1..15 load index
// words 1..15 of the row's nbmap line — all independent, issued one full
// iteration AHEAD of use so the next quad's line fetch overlaps the current
// quad's feats gathers.
__global__ __launch_bounds__(256) void gather_kernel(
    const float* __restrict__ feats,
    const unsigned* __restrict__ cnt,
    const unsigned* __restrict__ nbmap,
    float* __restrict__ out, int M, int nblk)
{
    // bijective XCD-chunked block swizzle (8 XCDs)
    int bid = blockIdx.x;
    int q8 = nblk >> 3, r8 = nblk & 7;
    int xcd = bid & 7, orig = bid >> 3;
    int swz = (xcd < r8 ? xcd * (q8 + 1) : r8 * (q8 + 1) + (xcd - r8) * q8) + orig;

    int lane = threadIdx.x & 63;
    int g  = lane >> 4;            // row within the quad
    int j  = lane & 15;            // channel quad / line word
    int gb = g << 4;
    int wv   = swz * 4 + (int)(threadIdx.x >> 6);
    int totW = nblk * 4;
    int nq   = (M + 3) >> 2;

    const f32x4* f4 = (const f32x4*)feats;

    int q = wv;
    unsigned u = 0;
    if (q < nq) {
        int row = q * 4 + g;
        if (row < M)
            u = (j == 0) ? __builtin_nontemporal_load(cnt + row)
                         : __builtin_nontemporal_load(nbmap + (size_t)row * NB_STRIDE + j);
    }
    for (; q < nq; q += totW) {
        int row = q * 4 + g;
        // issue next iteration's independent loads before consuming u
        unsigned un = 0;
        int qn = q + totW;
        if (qn < nq) {
            int rown = qn * 4 + g;
            if (rown < M)
                un = (j == 0) ? __builtin_nontemporal_load(cnt + rown)
                              : __builtin_nontemporal_load(nbmap + (size_t)rown * NB_STRIDE + j);
        }

        int c = __shfl((int)u, gb);           // count (uniform within group)
        f32x4 acc = {-INFINITY, -INFINITY, -INFINITY, -INFINITY};
        for (int r4 = 0; r4 < c; r4 += 4) {
#pragma unroll
            for (int k = 0; k < 4; ++k) {
                int h = r4 + k;
                if (h < c) {
                    int s = (h < 15) ? __shfl((int)u, gb + 1 + h)
                                     : (int)nbmap[(size_t)row * NB_STRIDE + 1 + h];
                    f32x4 v = f4[(size_t)s * 16 + j];
                    acc.x = fmaxf(acc.x, v.x);
                    acc.y = fmaxf(acc.y, v.y);
                    acc.z = fmaxf(acc.z, v.z);
                    acc.w = fmaxf(acc.w, v.w);
                }
            }
        }
        if (row < M) {
            if (c == 0) acc = (f32x4){0.f, 0.f, 0.f, 0.f};   // defensive (cannot happen)
            __builtin_nontemporal_store(acc, (f32x4*)out + (size_t)row * 16 + j);
        }
        u = un;
    }
}

// ---------------------------------------------------------------------------
// FALLBACK PATH (round-1 proven kernels) if ws is too small
// ---------------------------------------------------------------------------

__global__ __launch_bounds__(256) void build_hash_kernel(
    const int* __restrict__ coords, int N,
    unsigned long long* __restrict__ tab, unsigned tmask, int tshift)
{
    int i = blockIdx.x * blockDim.x + threadIdx.x;
    if (i >= N) return;
    int x = coords[i * 4 + 0];
    int y = coords[i * 4 + 1];
    int z = coords[i * 4 + 2];
    int b = coords[i * 4 + 3];
    unsigned key = ((unsigned)(b * RADIX + x + 1) * RADIX + (unsigned)(y + 1)) * RADIX
                   + (unsigned)(z + 1);
    unsigned long long entry = ((unsigned long long)key << 32) | (unsigned)i;
    unsigned slot = (key * 2654435761u) >> tshift;
    while (true) {
        unsigned long long prev = atomicCAS(&tab[slot], EMPTY_ENTRY, entry);
        if (prev == EMPTY_ENTRY) break;
        slot = (slot + 1) & tmask;
    }
}

__global__ __launch_bounds__(256) void pool_kernel(
    const float* __restrict__ feats,
    const int* __restrict__ down, int M,
    const unsigned long long* __restrict__ tab, unsigned tmask, int tshift,
    float* __restrict__ out)
{
    int wave = (int)((blockIdx.x * blockDim.x + threadIdx.x) >> 6);
    int lane = threadIdx.x & 63;
    if (wave >= M) return;

    const int* dc = down + (size_t)wave * 4;
    int dx = dc[0], dy = dc[1], dz = dc[2], db = dc[3];
    unsigned base = ((unsigned)(db * RADIX + dx + 1) * RADIX + (unsigned)(dy + 1)) * RADIX
                    + (unsigned)(dz + 1);

    int src = -1;
    if (lane < 27) {
        int ox = lane % 3 - 1;
        int oy = (lane / 3) % 3 - 1;
        int oz = lane / 9 - 1;
        int delta = ox * (RADIX * RADIX) + oy * RADIX + oz;
        unsigned key = (unsigned)((int)base + delta);
        unsigned slot = (key * 2654435761u) >> tshift;
        while (true) {
            unsigned long long e = tab[slot];
            if (e == EMPTY_ENTRY) break;
            if ((unsigned)(e >> 32) == key) { src = (int)(unsigned)e; break; }
            slot = (slot + 1) & tmask;
        }
    }
    unsigned long long mask = __ballot(src >= 0);
    float acc = -INFINITY;
    while (mask) {
        int bit = __ffsll(mask) - 1;
        int s = __shfl(src, bit);
        acc = fmaxf(acc, feats[(size_t)s * 64 + lane]);
        mask &= mask - 1;
    }
    out[(size_t)wave * 64 + lane] = isinf(acc) ? 0.0f : acc;
}

// ---------------------------------------------------------------------------

extern "C" void kernel_launch(void* const* d_in, const int* in_sizes, int n_in,
                              void* d_out, int out_size, void* d_ws, size_t ws_size,
                              hipStream_t stream)
{
    const float* feats  = (const float*)d_in[0];
    const int*   coords = (const int*)d_in[1];
    const int*   down   = (const int*)d_in[2];
    float*       out    = (float*)d_out;

    int N = in_sizes[1] / 4;
    int M = in_sizes[2] / 4;

    size_t map_bytes = (size_t)MAP_SLOTS * 4;                    // 16 MiB
    size_t cnt_bytes = ((size_t)M * 4 + 127) & ~(size_t)127;     // compact counts
    size_t nb_bytes  = (size_t)M * NB_STRIDE * 4;                // 128 B per row
    size_t need = map_bytes + cnt_bytes + nb_bytes;              // ~152 MB

    if (ws_size >= need) {
        unsigned* map   = (unsigned*)d_ws;
        unsigned* cnt   = (unsigned*)((char*)d_ws + map_bytes);
        unsigned* nbmap = (unsigned*)((char*)d_ws + map_bytes + cnt_bytes);

        hipMemsetAsync(map, 0xFF, map_bytes, stream);            // HW fill, ~3 us
        hipMemsetAsync(cnt, 0x00, (size_t)M * 4, stream);

        build_map_kernel<<<(M + 255) / 256, 256, 0, stream>>>(down, M, map);
        scatter_kernel<<<(N + 255) / 256, 256, 0, stream>>>(coords, N, map, cnt, nbmap);

        int nq = (M + 3) / 4;
        int nblk = (nq + 3) / 4;
        if (nblk > 2048) nblk = 2048;                            // 8192 waves = 32/CU
        gather_kernel<<<nblk, 256, 0, stream>>>(feats, cnt, nbmap, out, M, nblk);
    } else {
        int logT = 22;
        while (logT > 19 && ((size_t)8u << logT) > ws_size) logT--;
        unsigned T = 1u << logT;
        unsigned tmask = T - 1u;
        int tshift = 32 - logT;
        unsigned long long* tab = (unsigned long long*)d_ws;
        hipMemsetAsync(tab, 0xFF, (size_t)T * 8, stream);
        build_hash_kernel<<<(N + 255) / 256, 256, 0, stream>>>(coords, N, tab, tmask, tshift);
        pool_kernel<<<(M * 64 + 255) / 256, 256, 0, stream>>>(
            feats, down, M, tab, tmask, tshift, out);
    }
}

// Round 6
// 206.393 us; speedup vs baseline: 1.4065x; 1.0825x over previous
//
#include <hip/hip_runtime.h>
#include <cstdint>
#include <cstddef>

#define RADIX 258
#define EMPTY_ENTRY 0xFFFFFFFFFFFFFFFFULL
#define MAP_DIM 128                 // down coords are even, 0..254 -> /2 in 0..127
#define MAP_SLOTS (2 * MAP_DIM * MAP_DIM * MAP_DIM)   // 4.19M slots = 16 MiB
#define NB_WORDS 16                 // one 64-B sector per row: indices 0..14 (word 15 unused)
#define EXT_WORDS 12                // spill for indices 15..26 (never touched in practice)

typedef float f32x4 __attribute__((ext_vector_type(4)));

#define NEGINF4 ((f32x4){-INFINITY, -INFINITY, -INFINITY, -INFINITY})

// ---------------------------------------------------------------------------
// FAST PATH: dense parent map + compact cnt + 64-B nbmap rows + 2-stage gather
// ---------------------------------------------------------------------------

__global__ __launch_bounds__(256) void build_map_kernel(
    const int* __restrict__ down, int M, unsigned* __restrict__ map)
{
    int j = blockIdx.x * blockDim.x + threadIdx.x;
    if (j >= M) return;
    const int4 c = ((const int4*)down)[j];
    unsigned idx = (((unsigned)(c.w * MAP_DIM + (c.x >> 1)) * MAP_DIM)
                    + (unsigned)(c.y >> 1)) * MAP_DIM + (unsigned)(c.z >> 1);
    map[idx] = (unsigned)j;
}

// Append input row i to each existing candidate parent's list.
// cnt: compact L2-resident atomics. First 15 indices inline (64-B row),
// overflow (pos>=15, astronomically rare but legal) to ext.
__global__ __launch_bounds__(256) void scatter_kernel(
    const int* __restrict__ coords, int N,
    const unsigned* __restrict__ map,
    unsigned* __restrict__ cnt, unsigned* __restrict__ nbmap,
    unsigned* __restrict__ ext)
{
    int i = blockIdx.x * blockDim.x + threadIdx.x;
    if (i >= N) return;
    const int4 c = ((const int4*)coords)[i];
    int qx[2], qy[2], qz[2];
    int nx = 1, ny = 1, nz = 1;
    if (c.x & 1) { qx[0] = (c.x - 1) >> 1; if (c.x + 1 <= 254) qx[nx++] = (c.x + 1) >> 1; }
    else         { qx[0] = c.x >> 1; }
    if (c.y & 1) { qy[0] = (c.y - 1) >> 1; if (c.y + 1 <= 254) qy[ny++] = (c.y + 1) >> 1; }
    else         { qy[0] = c.y >> 1; }
    if (c.z & 1) { qz[0] = (c.z - 1) >> 1; if (c.z + 1 <= 254) qz[nz++] = (c.z + 1) >> 1; }
    else         { qz[0] = c.z >> 1; }
    unsigned bbase = (unsigned)(c.w * MAP_DIM);
    for (int ix = 0; ix < nx; ++ix) {
        unsigned xb = (bbase + (unsigned)qx[ix]) * MAP_DIM;
        for (int iy = 0; iy < ny; ++iy) {
            unsigned yb = (xb + (unsigned)qy[iy]) * MAP_DIM;
            for (int iz = 0; iz < nz; ++iz) {
                unsigned qi = map[yb + (unsigned)qz[iz]];
                if (qi != 0xFFFFFFFFu) {
                    unsigned pos = atomicAdd(&cnt[qi], 1u);
                    if (pos < 15)
                        nbmap[(size_t)qi * NB_WORDS + pos] = (unsigned)i;
                    else
                        ext[(size_t)qi * EXT_WORDS + (pos - 15)] = (unsigned)i;
                }
            }
        }
    }
}

// Persistent grid-stride gather; 4 rows per wave-iteration (16-lane groups;
// lane j = channel quad j). Two-stage pipeline:
//   stage L: line loads (cnt + 15 indices) issued 2 iterations ahead
//   stage F: feats loads (slots 0..3) issued 1 iteration ahead into w0..w3
//   stage C: consume v0..v3 (issued last iter), rare c>4 overflow serially, store
__global__ __launch_bounds__(256) void gather_kernel(
    const float* __restrict__ feats,
    const unsigned* __restrict__ cnt,
    const unsigned* __restrict__ nbmap,
    const unsigned* __restrict__ ext,
    float* __restrict__ out, int M, int nblk)
{
    // bijective XCD-chunked block swizzle (8 XCDs)
    int bid = blockIdx.x;
    int q8 = nblk >> 3, r8 = nblk & 7;
    int xcd = bid & 7, orig = bid >> 3;
    int swz = (xcd < r8 ? xcd * (q8 + 1) : r8 * (q8 + 1) + (xcd - r8) * q8) + orig;

    int lane = threadIdx.x & 63;
    int g  = lane >> 4;            // row within the quad
    int j  = lane & 15;            // channel quad / line word
    int gb = g << 4;
    int wv   = swz * 4 + (int)(threadIdx.x >> 6);
    int totW = nblk * 4;
    int nq   = (M + 3) >> 2;

    const f32x4* f4 = (const f32x4*)feats;

    // line load for quad qq -> one u32 per lane (lane 0 of group: cnt; lanes
    // 1..15: indices 0..14). Returns 0 (=> c=0) for out-of-range rows.
    auto load_line = [&](int qq) -> unsigned {
        unsigned v = 0;
        int rw = qq * 4 + g;
        if (qq < nq && rw < M)
            v = (j == 0) ? __builtin_nontemporal_load(cnt + rw)
                         : __builtin_nontemporal_load(nbmap + (size_t)rw * NB_WORDS + (j - 1));
        return v;
    };

    // ---- prologue -----------------------------------------------------
    int q = wv;
    unsigned uA = load_line(q);            // line for quad q   (consume this iter+1)
    unsigned uB = load_line(q + totW);     // line for quad q+T
    // issue feats for quad q from uA
    int cC = __shfl((int)uA, gb);
    f32x4 v0 = NEGINF4, v1 = NEGINF4, v2 = NEGINF4, v3 = NEGINF4;
    {
        int s0 = __shfl((int)uA, gb + 1);
        int s1 = __shfl((int)uA, gb + 2);
        int s2 = __shfl((int)uA, gb + 3);
        int s3 = __shfl((int)uA, gb + 4);
        if (0 < cC) v0 = f4[(size_t)s0 * 16 + j];
        if (1 < cC) v1 = f4[(size_t)s1 * 16 + j];
        if (2 < cC) v2 = f4[(size_t)s2 * 16 + j];
        if (3 < cC) v3 = f4[(size_t)s3 * 16 + j];
    }

    // ---- main loop ----------------------------------------------------
    for (; q < nq; ) {
        int qn = q + totW;
        unsigned uC = load_line(qn + totW);          // stage L: line 2 ahead

        // stage F: issue feats for quad qn from uB
        int cN = __shfl((int)uB, gb);
        f32x4 w0 = NEGINF4, w1 = NEGINF4, w2 = NEGINF4, w3 = NEGINF4;
        {
            int s0 = __shfl((int)uB, gb + 1);
            int s1 = __shfl((int)uB, gb + 2);
            int s2 = __shfl((int)uB, gb + 3);
            int s3 = __shfl((int)uB, gb + 4);
            if (0 < cN) w0 = f4[(size_t)s0 * 16 + j];
            if (1 < cN) w1 = f4[(size_t)s1 * 16 + j];
            if (2 < cN) w2 = f4[(size_t)s2 * 16 + j];
            if (3 < cN) w3 = f4[(size_t)s3 * 16 + j];
        }

        // stage C: consume quad q (v0..v3 issued one iteration ago)
        {
            int row = q * 4 + g;
            f32x4 acc = NEGINF4;
            if (0 < cC) { acc.x = fmaxf(acc.x, v0.x); acc.y = fmaxf(acc.y, v0.y);
                          acc.z = fmaxf(acc.z, v0.z); acc.w = fmaxf(acc.w, v0.w); }
            if (1 < cC) { acc.x = fmaxf(acc.x, v1.x); acc.y = fmaxf(acc.y, v1.y);
                          acc.z = fmaxf(acc.z, v1.z); acc.w = fmaxf(acc.w, v1.w); }
            if (2 < cC) { acc.x = fmaxf(acc.x, v2.x); acc.y = fmaxf(acc.y, v2.y);
                          acc.z = fmaxf(acc.z, v2.z); acc.w = fmaxf(acc.w, v2.w); }
            if (3 < cC) { acc.x = fmaxf(acc.x, v3.x); acc.y = fmaxf(acc.y, v3.y);
                          acc.z = fmaxf(acc.z, v3.z); acc.w = fmaxf(acc.w, v3.w); }
            // rare overflow: slots 4..cC-1 (serial; P(c>4) small)
            for (int h = 4; h < cC; ++h) {
                int s = (h < 15) ? __shfl((int)uA, gb + 1 + h)
                                 : (int)ext[(size_t)row * EXT_WORDS + (h - 15)];
                f32x4 vv = f4[(size_t)s * 16 + j];
                acc.x = fmaxf(acc.x, vv.x); acc.y = fmaxf(acc.y, vv.y);
                acc.z = fmaxf(acc.z, vv.z); acc.w = fmaxf(acc.w, vv.w);
            }
            if (row < M) {
                if (cC == 0) acc = (f32x4){0.f, 0.f, 0.f, 0.f};  // defensive
                __builtin_nontemporal_store(acc, (f32x4*)out + (size_t)row * 16 + j);
            }
        }

        // rotate pipeline
        uA = uB; uB = uC;
        v0 = w0; v1 = w1; v2 = w2; v3 = w3;
        cC = cN;
        q = qn;
    }
}

// ---------------------------------------------------------------------------
// FALLBACK PATH (round-1 proven kernels) if ws is too small
// ---------------------------------------------------------------------------

__global__ __launch_bounds__(256) void build_hash_kernel(
    const int* __restrict__ coords, int N,
    unsigned long long* __restrict__ tab, unsigned tmask, int tshift)
{
    int i = blockIdx.x * blockDim.x + threadIdx.x;
    if (i >= N) return;
    int x = coords[i * 4 + 0];
    int y = coords[i * 4 + 1];
    int z = coords[i * 4 + 2];
    int b = coords[i * 4 + 3];
    unsigned key = ((unsigned)(b * RADIX + x + 1) * RADIX + (unsigned)(y + 1)) * RADIX
                   + (unsigned)(z + 1);
    unsigned long long entry = ((unsigned long long)key << 32) | (unsigned)i;
    unsigned slot = (key * 2654435761u) >> tshift;
    while (true) {
        unsigned long long prev = atomicCAS(&tab[slot], EMPTY_ENTRY, entry);
        if (prev == EMPTY_ENTRY) break;
        slot = (slot + 1) & tmask;
    }
}

__global__ __launch_bounds__(256) void pool_kernel(
    const float* __restrict__ feats,
    const int* __restrict__ down, int M,
    const unsigned long long* __restrict__ tab, unsigned tmask, int tshift,
    float* __restrict__ out)
{
    int wave = (int)((blockIdx.x * blockDim.x + threadIdx.x) >> 6);
    int lane = threadIdx.x & 63;
    if (wave >= M) return;

    const int* dc = down + (size_t)wave * 4;
    int dx = dc[0], dy = dc[1], dz = dc[2], db = dc[3];
    unsigned base = ((unsigned)(db * RADIX + dx + 1) * RADIX + (unsigned)(dy + 1)) * RADIX
                    + (unsigned)(dz + 1);

    int src = -1;
    if (lane < 27) {
        int ox = lane % 3 - 1;
        int oy = (lane / 3) % 3 - 1;
        int oz = lane / 9 - 1;
        int delta = ox * (RADIX * RADIX) + oy * RADIX + oz;
        unsigned key = (unsigned)((int)base + delta);
        unsigned slot = (key * 2654435761u) >> tshift;
        while (true) {
            unsigned long long e = tab[slot];
            if (e == EMPTY_ENTRY) break;
            if ((unsigned)(e >> 32) == key) { src = (int)(unsigned)e; break; }
            slot = (slot + 1) & tmask;
        }
    }
    unsigned long long mask = __ballot(src >= 0);
    float acc = -INFINITY;
    while (mask) {
        int bit = __ffsll(mask) - 1;
        int s = __shfl(src, bit);
        acc = fmaxf(acc, feats[(size_t)s * 64 + lane]);
        mask &= mask - 1;
    }
    out[(size_t)wave * 64 + lane] = isinf(acc) ? 0.0f : acc;
}

// ---------------------------------------------------------------------------

extern "C" void kernel_launch(void* const* d_in, const int* in_sizes, int n_in,
                              void* d_out, int out_size, void* d_ws, size_t ws_size,
                              hipStream_t stream)
{
    const float* feats  = (const float*)d_in[0];
    const int*   coords = (const int*)d_in[1];
    const int*   down   = (const int*)d_in[2];
    float*       out    = (float*)d_out;

    int N = in_sizes[1] / 4;
    int M = in_sizes[2] / 4;

    size_t map_bytes = (size_t)MAP_SLOTS * 4;                    // 16 MiB
    size_t cnt_bytes = ((size_t)M * 4 + 127) & ~(size_t)127;
    size_t nb_bytes  = (size_t)M * NB_WORDS * 4;                 // 64 B per row
    size_t ext_bytes = (size_t)M * EXT_WORDS * 4;                // overflow spill
    size_t need = map_bytes + cnt_bytes + nb_bytes + ext_bytes;  // ~139 MB

    if (ws_size >= need) {
        char* p = (char*)d_ws;
        unsigned* map   = (unsigned*)p;                 p += map_bytes;
        unsigned* cnt   = (unsigned*)p;                 p += cnt_bytes;
        unsigned* nbmap = (unsigned*)p;                 p += nb_bytes;
        unsigned* ext   = (unsigned*)p;

        hipMemsetAsync(map, 0xFF, map_bytes, stream);            // HW fill
        hipMemsetAsync(cnt, 0x00, (size_t)M * 4, stream);

        build_map_kernel<<<(M + 255) / 256, 256, 0, stream>>>(down, M, map);
        scatter_kernel<<<(N + 255) / 256, 256, 0, stream>>>(coords, N, map, cnt, nbmap, ext);

        int nq = (M + 3) / 4;
        int nblk = (nq + 3) / 4;
        if (nblk > 2048) nblk = 2048;                            // 8192 waves = 32/CU
        gather_kernel<<<nblk, 256, 0, stream>>>(feats, cnt, nbmap, ext, out, M, nblk);
    } else {
        int logT = 22;
        while (logT > 19 && ((size_t)8u << logT) > ws_size) logT--;
        unsigned T = 1u << logT;
        unsigned tmask = T - 1u;
        int tshift = 32 - logT;
        unsigned long long* tab = (unsigned long long*)d_ws;
        hipMemsetAsync(tab, 0xFF, (size_t)T * 8, stream);
        build_hash_kernel<<<(N + 255) / 256, 256, 0, stream>>>(coords, N, tab, tmask, tshift);
        pool_kernel<<<(M * 64 + 255) / 256, 256, 0, stream>>>(
            feats, down, M, tab, tmask, tshift, out);
    }
}